// Round 1
// baseline (160.699 us; speedup 1.0000x reference)
//
#include <hip/hip_runtime.h>

// SpatialIndependentDistribution: B=64, C=16, H=64, W=64, NET=16, S=15
// Per-pixel fp32 kernel. Weights indexed by loop counters only (wave-uniform)
// so the compiler emits s_load -> constant cache -> v_fma with SGPR operand.

#define HW 4096          // H*W
#define S_STEPS 15
#define NPIX (64 * HW)   // B*H*W = 262144

__global__ __launch_bounds__(256, 4) void spatial_kernel(
    const float* __restrict__ samples,   // [64,16,64,64]
    const float* __restrict__ n1_b1,     // [16]
    const float* __restrict__ n1_w2,     // [16,16]
    const float* __restrict__ n1_b2,     // [16]
    const float* __restrict__ n1_w3,     // [2,16]
    const float* __restrict__ n1_b3,     // [2]
    const float* __restrict__ w1,        // [15,16,16] (pre-zeroed triangular)
    const float* __restrict__ b1,        // [15,16]
    const float* __restrict__ w2,        // [15,16,16]
    const float* __restrict__ b2,        // [15,16]
    const float* __restrict__ w3,        // [15,2,16]
    const float* __restrict__ b3,        // [15,2]
    float* __restrict__ out)             // [64,64,64]
{
    const float NEG_HALF_LOG_2PI = -0.91893853320467274f;  // -0.5*ln(2*pi)

    int p  = blockIdx.x * blockDim.x + threadIdx.x;        // 0..262143
    int b  = p >> 12;                                      // / 4096
    int hw = p & 4095;
    const float* xp = samples + (size_t)b * (16 * HW) + hw;

    // preload all 16 channels (coalesced across lanes for each c)
    float x[16];
    #pragma unroll
    for (int c = 0; c < 16; ++c) x[c] = xp[c * HW];

    float h1[16], h2[16];

    // ---- first channel: n1 net on zero input (params are input-independent) ----
    #pragma unroll
    for (int o = 0; o < 16; ++o) h1[o] = fmaxf(n1_b1[o], 0.0f);
    #pragma unroll
    for (int o = 0; o < 16; ++o) {
        float a = n1_b2[o];
        #pragma unroll
        for (int q = 0; q < 16; ++q) a = fmaf(n1_w2[o * 16 + q], h1[q], a);
        h2[o] = fmaxf(a, 0.0f);
    }
    float loc0 = n1_b3[0], lsc0 = n1_b3[1];
    #pragma unroll
    for (int q = 0; q < 16; ++q) {
        loc0 = fmaf(n1_w3[q],      h2[q], loc0);
        lsc0 = fmaf(n1_w3[16 + q], h2[q], lsc0);
    }
    float z0  = (x[0] - loc0) * __expf(-lsc0);
    float acc = fmaf(-0.5f * z0, z0, NEG_HALF_LOG_2PI - lsc0);

    // ---- S autoregressive steps (dense 16-wide; w1 already zero-padded) ----
    // s-loop kept rolled: per-iter body ~560 VALU instrs fits I-cache.
    for (int s = 0; s < S_STEPS; ++s) {
        const float* W1 = w1 + s * 256;
        const float* W2 = w2 + s * 256;
        const float* W3 = w3 + s * 32;

        #pragma unroll
        for (int o = 0; o < 16; ++o) {
            float a = b1[s * 16 + o];
            #pragma unroll
            for (int c = 0; c < 16; ++c) a = fmaf(W1[o * 16 + c], x[c], a);
            h1[o] = fmaxf(a, 0.0f);
        }
        #pragma unroll
        for (int o = 0; o < 16; ++o) {
            float a = b2[s * 16 + o];
            #pragma unroll
            for (int q = 0; q < 16; ++q) a = fmaf(W2[o * 16 + q], h1[q], a);
            h2[o] = fmaxf(a, 0.0f);
        }
        float lo = b3[s * 2 + 0];
        float ls = b3[s * 2 + 1];
        #pragma unroll
        for (int q = 0; q < 16; ++q) {
            lo = fmaf(W3[q],      h2[q], lo);
            ls = fmaf(W3[16 + q], h2[q], ls);
        }
        // reload x[s+1] from global (L1 hit) instead of dynamic reg-index
        float xn = xp[(s + 1) * HW];
        float zz = (xn - lo) * __expf(-ls);
        acc += fmaf(-0.5f * zz, zz, NEG_HALF_LOG_2PI - ls);
    }

    out[p] = acc;
}

extern "C" void kernel_launch(void* const* d_in, const int* in_sizes, int n_in,
                              void* d_out, int out_size, void* d_ws, size_t ws_size,
                              hipStream_t stream) {
    const float* samples = (const float*)d_in[0];
    // d_in[1] = n1_w1 (unused: first-channel input is zeros)
    const float* n1_b1   = (const float*)d_in[2];
    const float* n1_w2   = (const float*)d_in[3];
    const float* n1_b2   = (const float*)d_in[4];
    const float* n1_w3   = (const float*)d_in[5];
    const float* n1_b3   = (const float*)d_in[6];
    const float* w1      = (const float*)d_in[7];
    const float* b1      = (const float*)d_in[8];
    const float* w2      = (const float*)d_in[9];
    const float* b2      = (const float*)d_in[10];
    const float* w3      = (const float*)d_in[11];
    const float* b3      = (const float*)d_in[12];
    float* out = (float*)d_out;

    dim3 grid(NPIX / 256);
    dim3 block(256);
    spatial_kernel<<<grid, block, 0, stream>>>(
        samples, n1_b1, n1_w2, n1_b2, n1_w3, n1_b3,
        w1, b1, w2, b2, w3, b3, out);
}

// Round 2
// 143.341 us; speedup vs baseline: 1.1211x; 1.1211x over previous
//
#include <hip/hip_runtime.h>

// SpatialIndependentDistribution via chained MFMA 16x16x16 f16.
// B=64, C=16, H=64, W=64, NET=16, S=15 (+1 folded head step = 16 steps).
//
// Per wave: 16 pixels. Layers chained through MFMA C/D layout == B layout:
//   D element r of lane l = D[4*(l>>4)+r][l&15]  ==  B element i = B[4*(l>>4)+i][l&15]
// so relu+cvt(D) is directly the next layer's B fragment.
// Weights pre-swizzled into LDS as A-fragments; biases enter as MFMA C operand.
// W3 (2x16) replicated into rows {0,1} mod 4 -> all 64 lanes hold (loc,ls).
// Head (n1 net on zero input) = step 15 with A1=0, C1=n1_b1, target channel 0.

#define HW 4096
#define NSTEP 16            // 15 real steps + 1 head step

typedef _Float16 f16x4 __attribute__((ext_vector_type(4)));
typedef float    f32x4 __attribute__((ext_vector_type(4)));

__global__ __launch_bounds__(256, 4) void spatial_mfma_kernel(
    const float* __restrict__ samples,   // [64,16,64,64]
    const float* __restrict__ n1_b1,     // [16]
    const float* __restrict__ n1_w2,     // [16,16]
    const float* __restrict__ n1_b2,     // [16]
    const float* __restrict__ n1_w3,     // [2,16]
    const float* __restrict__ n1_b3,     // [2]
    const float* __restrict__ w1,        // [15,16,16] zero-padded triangular
    const float* __restrict__ b1,        // [15,16]
    const float* __restrict__ w2,        // [15,16,16]
    const float* __restrict__ b2,        // [15,16]
    const float* __restrict__ w3,        // [15,2,16]
    const float* __restrict__ b3,        // [15,2]
    float* __restrict__ out)             // [64,64,64]
{
    __shared__ _Float16 fragA[NSTEP * 3 * 256];   // [(s*3+layer)*256 + lane*4 + i]
    __shared__ float    biasLDS[NSTEP * 2 * 16];  // [s][layer(1,2)][o]
    __shared__ float    c3LDS[NSTEP * 4];         // [s][{b3_loc, b3_ls, 0, 0}]

    const int tid = threadIdx.x;

    // ---- stage pre-swizzled A fragments (f32 -> f16) ----
    // A-frag: lane l holds A[row=l&15][k=4*(l>>4)+i], i=0..3
    for (int idx = tid; idx < NSTEP * 3 * 256; idx += 256) {
        int sl    = idx >> 8;            // s*3+layer, 0..47 (uniform per iter)
        int s     = sl / 3;
        int layer = sl - 3 * s;
        int lane  = (idx >> 2) & 63;
        int i     = idx & 3;
        int row   = lane & 15;
        int k     = ((lane >> 4) << 2) + i;
        float v;
        if (layer == 0) {
            v = (s < 15) ? w1[s * 256 + row * 16 + k] : 0.0f;      // head: A1 = 0
        } else if (layer == 1) {
            v = (s < 15) ? w2[s * 256 + row * 16 + k] : n1_w2[row * 16 + k];
        } else {
            int r4 = row & 3;            // replicate W3 rows into {0,1} mod 4
            const float* W3 = (s < 15) ? (w3 + s * 32) : n1_w3;
            v = (r4 == 0) ? W3[k] : (r4 == 1) ? W3[16 + k] : 0.0f;
        }
        fragA[idx] = (_Float16)v;        // idx == sl*256 + lane*4 + i
    }
    // ---- biases for layers 1,2 (enter MFMA as C operand) ----
    for (int idx = tid; idx < NSTEP * 2 * 16; idx += 256) {
        int s     = idx >> 5;
        int layer = (idx >> 4) & 1;
        int o     = idx & 15;
        float v = (s < 15) ? (layer ? b2[s * 16 + o] : b1[s * 16 + o])
                           : (layer ? n1_b2[o]       : n1_b1[o]);
        biasLDS[idx] = v;
    }
    if (tid < NSTEP * 4) {
        int s = tid >> 2, j = tid & 3;
        float v = 0.0f;
        if (j < 2) v = (s < 15) ? b3[s * 2 + j] : n1_b3[j];
        c3LDS[tid] = v;
    }
    __syncthreads();

    // ---- per-wave compute: 16 pixels ----
    const int lane = tid & 63;
    const int wv   = tid >> 6;
    const int q    = lane >> 4;          // quad 0..3
    const int c    = lane & 15;          // pixel column within group
    const int p    = (blockIdx.x * 4 + wv) * 16 + c;   // global pixel
    const int b    = p >> 12;
    const int hw   = p & 4095;
    const float* base = samples + ((size_t)b << 16) + hw;   // b*16*4096 + hw

    // B fragment of X: lane holds channels {4q+i} of its pixel
    f16x4 bx;
    #pragma unroll
    for (int i = 0; i < 4; ++i)
        bx[i] = (_Float16)base[(size_t)(((q << 2) + i)) << 12];

    float acc = 0.0f;
    const float NEG_HALF_LOG_2PI = -0.91893853320467274f;

    for (int s = 0; s < NSTEP; ++s) {
        const f16x4 a1 = *(const f16x4*)&fragA[(s * 3 + 0) * 256 + lane * 4];
        const f16x4 a2 = *(const f16x4*)&fragA[(s * 3 + 1) * 256 + lane * 4];
        const f16x4 a3 = *(const f16x4*)&fragA[(s * 3 + 2) * 256 + lane * 4];
        f32x4 c1 = *(const f32x4*)&biasLDS[(s * 2 + 0) * 16 + (q << 2)];
        f32x4 c2 = *(const f32x4*)&biasLDS[(s * 2 + 1) * 16 + (q << 2)];
        f32x4 c3 = *(const f32x4*)&c3LDS[s * 4];

        f32x4 d1 = __builtin_amdgcn_mfma_f32_16x16x16f16(a1, bx, c1, 0, 0, 0);
        f16x4 h1;
        #pragma unroll
        for (int r = 0; r < 4; ++r) h1[r] = (_Float16)fmaxf(d1[r], 0.0f);

        f32x4 d2 = __builtin_amdgcn_mfma_f32_16x16x16f16(a2, h1, c2, 0, 0, 0);
        f16x4 h2;
        #pragma unroll
        for (int r = 0; r < 4; ++r) h2[r] = (_Float16)fmaxf(d2[r], 0.0f);

        f32x4 d3 = __builtin_amdgcn_mfma_f32_16x16x16f16(a3, h2, c3, 0, 0, 0);
        // d3[0] = loc, d3[1] = log_scale (replicated in every quad)

        float xn = base[(size_t)(((s + 1) & 15)) << 12];  // fp32 target sample
        float ls = d3[1];
        float z  = (xn - d3[0]) * __expf(-ls);
        acc += fmaf(-0.5f * z, z, NEG_HALF_LOG_2PI - ls);
    }

    if (q == 0) out[p] = acc;   // quads 1..3 are replicas
}

extern "C" void kernel_launch(void* const* d_in, const int* in_sizes, int n_in,
                              void* d_out, int out_size, void* d_ws, size_t ws_size,
                              hipStream_t stream) {
    const float* samples = (const float*)d_in[0];
    // d_in[1] = n1_w1 unused (first-channel input is zeros)
    const float* n1_b1   = (const float*)d_in[2];
    const float* n1_w2   = (const float*)d_in[3];
    const float* n1_b2   = (const float*)d_in[4];
    const float* n1_w3   = (const float*)d_in[5];
    const float* n1_b3   = (const float*)d_in[6];
    const float* w1      = (const float*)d_in[7];
    const float* b1      = (const float*)d_in[8];
    const float* w2      = (const float*)d_in[9];
    const float* b2      = (const float*)d_in[10];
    const float* w3      = (const float*)d_in[11];
    const float* b3      = (const float*)d_in[12];
    float* out = (float*)d_out;

    // 262144 pixels / 16 per wave = 16384 waves / 4 per block = 4096 blocks
    spatial_mfma_kernel<<<dim3(4096), dim3(256), 0, stream>>>(
        samples, n1_b1, n1_w2, n1_b2, n1_w3, n1_b3,
        w1, b1, w2, b2, w3, b3, out);
}

// Round 4
// 106.177 us; speedup vs baseline: 1.5135x; 1.3500x over previous
//
#include <hip/hip_runtime.h>

// SpatialIndependentDistribution, round 4 (round-3 structure, compile fix).
// Kernel A: build swizzled weight package + head scalars into ws (once per launch).
// Kernel B: 64 pixels/wave, chained MFMA 16x16x16 f16, no LDS, fp32 relu + packed
//           cvt, quad-parallel epilogue (quad q handles chain q), coalesced I/O.

#define NEG_HALF_LOG_2PI -0.91893853320467274f

typedef _Float16 f16x4 __attribute__((ext_vector_type(4)));
typedef __fp16   hf2   __attribute__((ext_vector_type(2)));
typedef float    f32x4 __attribute__((ext_vector_type(4)));

// ws package layout (bytes)
#define OFF_A    0        // [15][3][256] f16 = 23040 B, A-fragments lane-swizzled
#define OFF_C12  23040    // [15][2][16] f32  = 1920 B, b1/b2 biases (MFMA C operand)
#define OFF_C3   24960    // [15][4] f32      = 240 B, {b3_loc, b3_ls, 0, 0}
#define OFF_HD   25200    // {loc0, exp(-lsc0), lsc0, 16K - lsc0} f32 = 16 B

__device__ inline f16x4 relu_pack(f32x4 d) {
    hf2 p0 = __builtin_amdgcn_cvt_pkrtz(fmaxf(d[0], 0.0f), fmaxf(d[1], 0.0f));
    hf2 p1 = __builtin_amdgcn_cvt_pkrtz(fmaxf(d[2], 0.0f), fmaxf(d[3], 0.0f));
    f16x4 r;
    __builtin_memcpy(&r, &p0, 4);
    __builtin_memcpy((char*)&r + 4, &p1, 4);
    return r;
}

__global__ void build_pkg(
    const float* __restrict__ n1_b1, const float* __restrict__ n1_w2,
    const float* __restrict__ n1_b2, const float* __restrict__ n1_w3,
    const float* __restrict__ n1_b3,
    const float* __restrict__ w1, const float* __restrict__ b1,
    const float* __restrict__ w2, const float* __restrict__ b2,
    const float* __restrict__ w3, const float* __restrict__ b3,
    unsigned char* __restrict__ ws)
{
    _Float16* A  = (_Float16*)(ws + OFF_A);
    float* C12   = (float*)(ws + OFF_C12);
    float* C3    = (float*)(ws + OFF_C3);
    float* HD    = (float*)(ws + OFF_HD);
    const int tid = threadIdx.x;   // 1024 threads, 1 block

    // A-fragments: lane l holds A[row=l&15][k=4*(l>>4)+i]
    #pragma unroll 4
    for (int idx = tid; idx < 15 * 3 * 256; idx += 1024) {
        int sl    = idx >> 8;          // s*3+layer
        int s     = sl / 3;
        int layer = sl - 3 * s;
        int lane  = (idx >> 2) & 63;
        int i     = idx & 3;
        int row   = lane & 15;
        int k     = ((lane >> 4) << 2) + i;
        float v;
        if (layer == 0)      v = w1[s * 256 + row * 16 + k];
        else if (layer == 1) v = w2[s * 256 + row * 16 + k];
        else {
            int r4 = row & 3;          // replicate W3 rows into {0,1} mod 4
            v = (r4 == 0) ? w3[s * 32 + k] : (r4 == 1) ? w3[s * 32 + 16 + k] : 0.0f;
        }
        A[idx] = (_Float16)v;
    }
    if (tid < 15 * 2 * 16) {
        int s = tid >> 5, layer = (tid >> 4) & 1, o = tid & 15;
        C12[tid] = layer ? b2[s * 16 + o] : b1[s * 16 + o];
    }
    if (tid < 60) {
        int s = tid >> 2, j = tid & 3;
        C3[tid] = (j < 2) ? b3[s * 2 + j] : 0.0f;
    }

    // head: n1 net applied to zero input (input-independent scalars)
    __shared__ float h1s[16], h2s[16];
    if (tid < 16) h1s[tid] = fmaxf(n1_b1[tid], 0.0f);
    __syncthreads();
    if (tid < 16) {
        float a = n1_b2[tid];
        #pragma unroll
        for (int qq = 0; qq < 16; ++qq) a = fmaf(n1_w2[tid * 16 + qq], h1s[qq], a);
        h2s[tid] = fmaxf(a, 0.0f);
    }
    __syncthreads();
    if (tid == 0) {
        float lo = n1_b3[0], ls = n1_b3[1];
        #pragma unroll
        for (int qq = 0; qq < 16; ++qq) {
            lo = fmaf(n1_w3[qq],      h2s[qq], lo);
            ls = fmaf(n1_w3[16 + qq], h2s[qq], ls);
        }
        HD[0] = lo;
        HD[1] = __expf(-ls);
        HD[2] = ls;
        HD[3] = 16.0f * NEG_HALF_LOG_2PI - ls;
    }
}

__global__ __launch_bounds__(256, 4) void spatial_main(
    const float* __restrict__ samples,          // [64,16,64,64]
    const unsigned char* __restrict__ ws,
    float* __restrict__ out)                    // [64,64,64]
{
    const int tid   = threadIdx.x;
    const int lane  = tid & 63;
    const int wv    = tid >> 6;
    const int q     = lane >> 4;
    const int col   = lane & 15;
    const int lane4 = lane << 2;
    const int q4    = q << 2;

    const _Float16* A  = (const _Float16*)(ws + OFF_A);
    const float* C12   = (const float*)(ws + OFF_C12);
    const float* C3    = (const float*)(ws + OFF_C3);
    const float* HD    = (const float*)(ws + OFF_HD);

    const int pbase = blockIdx.x * 256 + wv * 64;       // wave's first pixel
    const int b     = pbase >> 12;
    const int hw    = pbase & 4095;
    const float* xw = samples + ((size_t)b << 16) + hw; // + ch*4096 + 0..63

    // B-fragments: chain ch = pixels pbase+16ch..+15; lane holds ch 4q..4q+3
    f16x4 bx[4];
    #pragma unroll
    for (int ch = 0; ch < 4; ++ch)
        #pragma unroll
        for (int i = 0; i < 4; ++i)
            bx[ch][i] = (_Float16)xw[((q4 + i) << 12) + (ch << 4) + col];

    float accz, accl = 0.0f;
    {   // head: channel 0, exact fp32 path with precomputed scalars
        float x0 = xw[lane];
        float z0 = (x0 - HD[0]) * HD[1];
        accz = z0 * z0;
    }

    #pragma unroll
    for (int s = 0; s < 15; ++s) {
        f16x4 a1 = *(const f16x4*)(A + (s * 3 + 0) * 256 + lane4);
        f16x4 a2 = *(const f16x4*)(A + (s * 3 + 1) * 256 + lane4);
        f16x4 a3 = *(const f16x4*)(A + (s * 3 + 2) * 256 + lane4);
        f32x4 c1 = *(const f32x4*)(C12 + (s * 2 + 0) * 16 + q4);
        f32x4 c2 = *(const f32x4*)(C12 + (s * 2 + 1) * 16 + q4);
        f32x4 c3 = *(const f32x4*)(C3 + s * 4);

        float loc_q[4], ls_q[4];
        #pragma unroll
        for (int ch = 0; ch < 4; ++ch) {
            f32x4 d1 = __builtin_amdgcn_mfma_f32_16x16x16f16(a1, bx[ch], c1, 0, 0, 0);
            f16x4 h1 = relu_pack(d1);
            f32x4 d2 = __builtin_amdgcn_mfma_f32_16x16x16f16(a2, h1, c2, 0, 0, 0);
            f16x4 h2 = relu_pack(d2);
            f32x4 d3 = __builtin_amdgcn_mfma_f32_16x16x16f16(a3, h2, c3, 0, 0, 0);
            loc_q[ch] = d3[0];          // rows 0 mod 4 -> loc (all quads identical)
            ls_q[ch]  = d3[1];          // rows 1 mod 4 -> log_scale
        }
        // quad q takes over chain q's epilogue -> 1 coalesced xn load, no replication
        float loc = q == 0 ? loc_q[0] : q == 1 ? loc_q[1] : q == 2 ? loc_q[2] : loc_q[3];
        float ls  = q == 0 ? ls_q[0]  : q == 1 ? ls_q[1]  : q == 2 ? ls_q[2]  : ls_q[3];
        float xn  = xw[((s + 1) << 12) + lane];      // channel s+1, pixel pbase+lane
        float z   = (xn - loc) * __expf(-ls);
        accz = fmaf(z, z, accz);
        accl += ls;
    }

    // out = -0.5*accz - accl + (16*K - lsc0); all 64 lanes write (coalesced)
    out[pbase + lane] = fmaf(-0.5f, accz, HD[3] - accl);
}

extern "C" void kernel_launch(void* const* d_in, const int* in_sizes, int n_in,
                              void* d_out, int out_size, void* d_ws, size_t ws_size,
                              hipStream_t stream) {
    const float* samples = (const float*)d_in[0];
    // d_in[1] = n1_w1 unused (first-channel input is zeros)
    const float* n1_b1   = (const float*)d_in[2];
    const float* n1_w2   = (const float*)d_in[3];
    const float* n1_b2   = (const float*)d_in[4];
    const float* n1_w3   = (const float*)d_in[5];
    const float* n1_b3   = (const float*)d_in[6];
    const float* w1      = (const float*)d_in[7];
    const float* b1      = (const float*)d_in[8];
    const float* w2      = (const float*)d_in[9];
    const float* b2      = (const float*)d_in[10];
    const float* w3      = (const float*)d_in[11];
    const float* b3      = (const float*)d_in[12];
    float* out = (float*)d_out;
    unsigned char* ws = (unsigned char*)d_ws;

    build_pkg<<<dim3(1), dim3(1024), 0, stream>>>(
        n1_b1, n1_w2, n1_b2, n1_w3, n1_b3, w1, b1, w2, b2, w3, b3, ws);

    // 262144 pixels / 64 per wave / 4 waves per block = 1024 blocks (grid-resident)
    spatial_main<<<dim3(1024), dim3(256), 0, stream>>>(samples, ws, out);
}